// Round 2
// baseline (253.830 us; speedup 1.0000x reference)
//
#include <hip/hip_runtime.h>
#include <hip/hip_bf16.h>

// Hex-grid VIN, algebraically reduced:
//   v_new[r][u][v] = M[u][v] * max_a( gm[src_a] + 0.9*v[src_a] )[shifted_a]
//   gm = M * goals_axial,  M = axial_mask * (1 - obstacle_axial), binary & idempotent.
// 20 Jacobi sweeps LDS-resident, then 4 final q evaluations per batch.

#define EE     25
#define HH     37
#define ST     26               // padded leading dim (kills pow-2 strides)
#define NROT   6
#define PLANE  (HH * ST)        // 962
#define VOL    (NROT * PLANE)   // 5772
#define HE     (HH * EE)        // 925
#define NCELL  (NROT * HE)      // 5550
#define KMAX   ((NCELL + 255) / 256)   // 22 cells per thread
#define GAM    0.9f

__device__ __forceinline__ float bf2f(unsigned short h) {
    return __uint_as_float(((unsigned int)h) << 16);
}
__device__ __forceinline__ unsigned short f2bf(float f) {  // RNE
    unsigned int u = __float_as_uint(f);
    unsigned int r = 0x7FFFu + ((u >> 16) & 1u);
    return (unsigned short)((u + r) >> 16);
}

// Inputs are exactly {0.0f, 1.0f}. float32 1.0 has zero low-16 bits, so even
// uint16 positions are all 0x0000 iff the buffer is f32; under bf16 ~1% of
// them are 0x3F80. Sets flag=1 iff bf16.
__global__ void detect_kernel(const unsigned short* __restrict__ g, int n_u16,
                              unsigned int* __restrict__ flag) {
    unsigned int acc = 0;
    int stride = gridDim.x * blockDim.x;
    for (int e = blockIdx.x * blockDim.x + threadIdx.x; 2 * e < n_u16; e += stride)
        acc |= g[2 * e];
    bool any = __any(acc != 0);
    if (any && (threadIdx.x & 63) == 0) atomicOr(flag, 1u);
}

template <int IS_BF16>
__global__ __launch_bounds__(256) void vin_kernel(
    const void* __restrict__ goals_, const int* __restrict__ state,
    const void* __restrict__ obst_,  const int* __restrict__ nitp,
    void* __restrict__ out_, const unsigned int* __restrict__ flag)
{
    if (flag && *(volatile const unsigned int*)flag != (unsigned int)IS_BF16) return;

    __shared__ unsigned short sM[PLANE];   // mask bits (bf16 0/1, exact)
    __shared__ unsigned short sG[VOL];     // gm bits (bf16 0/1, exact)
    __shared__ float          sV[VOL];     // value field (f32)

    const int b = blockIdx.x, tid = threadIdx.x;

    int n = nitp[0];                       // robust scalar read
    if (n < 0 || n > 1000) {
        float f = __int_as_float(n);
        n = (f >= 0.f && f <= 1000.f) ? (int)(f + 0.5f) : 20;
    }

    const unsigned short* g16 = (const unsigned short*)goals_ + (size_t)b * (NROT * EE * EE);
    const float*          g32 = (const float*)goals_          + (size_t)b * (NROT * EE * EE);
    const unsigned short* o16 = (const unsigned short*)obst_  + (size_t)b * (EE * EE);
    const float*          o32 = (const float*)obst_           + (size_t)b * (EE * EE);

    // ---- M over axial grid (pad col v==25 zeroed) ----
    for (int idx = tid; idx < PLANE; idx += 256) {
        int u = idx / ST, v = idx - u * ST;
        float m = 0.f;
        if (v < EE) {
            int i = u + (v >> 1) - 12;     // axial(u,v) -> offset row i
            if (i >= 0 && i < EE) {
                float ob = IS_BF16 ? bf2f(o16[i * EE + v]) : o32[i * EE + v];
                m = 1.f - ob;
            }
        }
        sM[idx] = f2bf(m);
    }
    __syncthreads();

    // ---- gm = M * goals_axial; zero value field ----
    for (int idx = tid; idx < VOL; idx += 256) {
        int r = idx / PLANE, rem = idx - r * PLANE;
        int u = rem / ST, v = rem - u * ST;
        float gv = 0.f;
        if (v < EE) {
            int i = u + (v >> 1) - 12;
            if (i >= 0 && i < EE) {
                float g = IS_BF16 ? bf2f(g16[(r * EE + i) * EE + v])
                                  : g32[(r * EE + i) * EE + v];
                gv = bf2f(sM[rem]) * g;
            }
        }
        sG[idx] = f2bf(gv);
        sV[idx] = 0.f;
    }
    __syncthreads();

    // ---- n Jacobi sweeps (register-staged, single LDS value buffer) ----
    float qv[KMAX];
    int   qo[KMAX];
    for (int it = 0; it < n; ++it) {
        #pragma unroll
        for (int k = 0; k < KMAX; ++k) {
            int idx = tid + 256 * k;
            if (idx < NCELL) {
                int r = idx / HE, rem = idx - r * HE;
                int u = rem / EE, v = rem - u * EE;
                // fwd shift per rotation: DU={0,1,1,0,-1,-1}, DV={1,0,-1,-1,0,1}
                int du = ((r == 1) | (r == 2)) ? 1 : (((r == 4) | (r == 5)) ? -1 : 0);
                int dv = ((r == 0) | (r == 5)) ? 1 : (((r == 2) | (r == 3)) ? -1 : 0);
                int base = r * PLANE, off = u * ST + v;

                float q0 = 0.f, q1 = 0.f;
                int ua = u + du, va = v + dv;                   // a=0 forward
                if (ua >= 0 && ua < HH && va >= 0 && va < EE) {
                    int o = base + ua * ST + va;
                    q0 = bf2f(sG[o]) + GAM * sV[o];
                }
                int ub = u - du, vb = v - dv;                   // a=1 backward
                if (ub >= 0 && ub < HH && vb >= 0 && vb < EE) {
                    int o = base + ub * ST + vb;
                    q1 = bf2f(sG[o]) + GAM * sV[o];
                }
                int r2 = (r == 5) ? 0 : r + 1;                  // a=2 turn
                int r3 = (r == 0) ? 5 : r - 1;                  // a=3 turn
                int o2 = r2 * PLANE + off, o3 = r3 * PLANE + off;
                float q2 = bf2f(sG[o2]) + GAM * sV[o2];
                float q3 = bf2f(sG[o3]) + GAM * sV[o3];

                qv[k] = bf2f(sM[off]) * fmaxf(fmaxf(q0, q1), fmaxf(q2, q3));
                qo[k] = base + off;
            }
        }
        __syncthreads();
        #pragma unroll
        for (int k = 0; k < KMAX; ++k) {
            int idx = tid + 256 * k;
            if (idx < NCELL) sV[qo[k]] = qv[k];
        }
        __syncthreads();
    }

    // ---- final gather: q_N[a] at (rot=(alpha+1)%6, uu, sv) ----
    if (tid < 4) {
        int alpha = state[b * 3 + 0];
        int su    = state[b * 3 + 1];
        int sv    = state[b * 3 + 2];
        int rq = (alpha + 1) % NROT;
        int uu = su - (sv >> 1) + 12;

        int du = ((rq == 1) | (rq == 2)) ? 1 : (((rq == 4) | (rq == 5)) ? -1 : 0);
        int dv = ((rq == 0) | (rq == 5)) ? 1 : (((rq == 2) | (rq == 3)) ? -1 : 0);

        int rr, tu, tv;
        if      (tid == 0) { rr = rq;                     tu = uu + du; tv = sv + dv; }
        else if (tid == 1) { rr = rq;                     tu = uu - du; tv = sv - dv; }
        else if (tid == 2) { rr = (rq == 5) ? 0 : rq + 1; tu = uu;      tv = sv;      }
        else               { rr = (rq == 0) ? 5 : rq - 1; tu = uu;      tv = sv;      }

        float q = 0.f;
        if (tu >= 0 && tu < HH && tv >= 0 && tv < EE) {
            int o = rr * PLANE + tu * ST + tv;
            q = bf2f(sG[o]) + GAM * sV[o];
        }
        float res = bf2f(sM[uu * ST + sv]) * q;
        if (IS_BF16) ((unsigned short*)out_)[b * 4 + tid] = f2bf(res);
        else         ((float*)out_)[b * 4 + tid]          = res;
    }
}

extern "C" void kernel_launch(void* const* d_in, const int* in_sizes, int n_in,
                              void* d_out, int out_size, void* d_ws, size_t ws_size,
                              hipStream_t stream) {
    const int* state = (const int*)d_in[1];
    const int* nit   = (const int*)d_in[3];
    int B = in_sizes[1] / 3;
    if (B <= 0) B = in_sizes[0] / (NROT * EE * EE);

    if (ws_size >= 4 && d_ws) {
        unsigned int* flag = (unsigned int*)d_ws;
        hipMemsetAsync(flag, 0, 4, stream);
        detect_kernel<<<64, 256, 0, stream>>>((const unsigned short*)d_in[0],
                                              in_sizes[0], flag);
        vin_kernel<1><<<B, 256, 0, stream>>>(d_in[0], state, d_in[2], nit, d_out, flag);
        vin_kernel<0><<<B, 256, 0, stream>>>(d_in[0], state, d_in[2], nit, d_out, flag);
    } else {
        // no workspace: assume bf16 (flag=null means "run unconditionally")
        vin_kernel<1><<<B, 256, 0, stream>>>(d_in[0], state, d_in[2], nit, d_out,
                                             (const unsigned int*)nullptr);
    }
}

// Round 3
// 86.944 us; speedup vs baseline: 2.9195x; 2.9195x over previous
//
#include <hip/hip_runtime.h>
#include <hip/hip_bf16.h>

// Hex-grid VIN, reduced to a single-field Jacobi iteration on W = gm + 0.9*v:
//   W[c] <- gm[c] + 0.9*m[c]*max(W[o0],W[o1],W[o2],W[o3])
// gm = m*goals_axial in {0,1}; m = axial_mask*(1-obstacle) in {0,1}.
// Padded plane (39 rows x 26 cols, interior rows 1..37, pad col 25) makes every
// shift land on an always-zero pad cell -> no bounds checks in the hot loop.

#define EE    25
#define HH    37
#define ST    26
#define PR    39                  // 37 interior rows + top/bottom pad
#define PLANE (PR * ST)           // 1014
#define NROT  6
#define VOL   (NROT * PLANE)      // 6084
#define NPAIR (HH * 13)           // 481 (13 float2-pairs per row)
#define NTH   512
#define GAM   0.9f
#define GELEM (NROT * EE * EE)    // 3750
#define OELEM (EE * EE)           // 625

__device__ __forceinline__ float bf2f(unsigned short h) {
    return __uint_as_float(((unsigned int)h) << 16);
}
__device__ __forceinline__ unsigned short f2bf(float f) {  // RNE
    unsigned int u = __float_as_uint(f);
    return (unsigned short)((u + 0x7FFFu + ((u >> 16) & 1u)) >> 16);
}

__global__ __launch_bounds__(NTH, 4) void vin_kernel(
    const void* __restrict__ goals_, const int* __restrict__ state,
    const void* __restrict__ obst_,  const int* __restrict__ nitp,
    void* __restrict__ out_)
{
    __shared__ float sA[VOL];
    __shared__ float sB[VOL];
    __shared__ int   sFlag;

    const int b = blockIdx.x, t = threadIdx.x;

    // ---- dtype detect, per block. f32 {0,1} values have all-even-u16 == 0;
    // bf16 goal/obstacle ones show up at even global u16 positions. A batch
    // with zero goals everywhere outputs 0 under either interpretation, so a
    // per-block decision is safe.
    if (t == 0) sFlag = 0;
    __syncthreads();
    {
        const unsigned short* gu = (const unsigned short*)goals_;
        const unsigned short* ou = (const unsigned short*)obst_;
        unsigned int acc = 0;
        size_t gbase = (size_t)b * GELEM;              // even (3750 even)
        for (int e = t; e < GELEM / 2; e += NTH) acc |= gu[gbase + 2 * (size_t)e];
        size_t obase = (size_t)b * OELEM;              // parity alternates
        size_t ostart = obase + (obase & 1);
        int ocnt = (OELEM - (int)(obase & 1) + 1) >> 1;
        for (int e = t; e < ocnt; e += NTH) acc |= ou[ostart + 2 * (size_t)e];
        if (acc) atomicOr(&sFlag, 1);
    }
    int n = nitp[0];                                    // robust scalar read
    if (n < 0 || n > 1000) {
        float f = __int_as_float(n);
        n = (f >= 0.f && f <= 1000.f) ? (int)(f + 0.5f) : 20;
    }
    __syncthreads();
    const bool isbf = (sFlag != 0);

    const unsigned short* g16 = (const unsigned short*)goals_ + (size_t)b * GELEM;
    const float*          g32 = (const float*)goals_          + (size_t)b * GELEM;
    const unsigned short* o16 = (const unsigned short*)obst_  + (size_t)b * OELEM;
    const float*          o32 = (const float*)obst_           + (size_t)b * OELEM;

    // ---- zero both W buffers (pads must be 0 and stay 0)
    for (int i = t; i < VOL; i += NTH) { sA[i] = 0.f; sB[i] = 0.f; }
    __syncthreads();

    // ---- per-thread iteration-invariant constants + W_0 = gm
    const bool active = (t < NPAIR);
    const int u  = t / 13;
    const int p  = t - 13 * u;
    const int off = (u + 1) * ST + 2 * p;               // padded, 8B-aligned
    float aa0 = 0.f, aa1 = 0.f;                         // gamma * m per column
    float gx[NROT], gy[NROT];                           // gm per rotation
    #pragma unroll
    for (int r = 0; r < NROT; ++r) { gx[r] = 0.f; gy[r] = 0.f; }

    if (active) {
        #pragma unroll
        for (int j = 0; j < 2; ++j) {
            int v = 2 * p + j;
            float m = 0.f;
            int i = u - 12 + (v >> 1);                  // offset row for (u,v)
            if (v < EE && i >= 0 && i < EE)
                m = 1.f - (isbf ? bf2f(o16[i * EE + v]) : o32[i * EE + v]);
            if (j == 0) aa0 = GAM * m; else aa1 = GAM * m;
            #pragma unroll
            for (int r = 0; r < NROT; ++r) {
                float g = 0.f;
                if (v < EE && i >= 0 && i < EE) {
                    float gv = isbf ? bf2f(g16[(r * EE + i) * EE + v])
                                    : g32[(r * EE + i) * EE + v];
                    g = m * gv;
                }
                if (j == 0) gx[r] = g; else gy[r] = g;
                sA[r * PLANE + off + j] = g;
            }
        }
    }
    __syncthreads();

    // ---- n Jacobi sweeps, double-buffered, ONE barrier per sweep
    float* cur = sA;
    float* nxt = sB;
    for (int it = 0; it < n; ++it) {
        if (active) {
            float rx[NROT], ry[NROT];
            #pragma unroll
            for (int r = 0; r < NROT; ++r) {
                // fwd shift per rotation: d = du*ST+dv, DU={0,1,1,0,-1,-1}, DV={1,0,-1,-1,0,1}
                const int d  = (r == 0) ? 1 : (r == 1) ? ST : (r == 2) ? (ST - 1)
                             : (r == 3) ? -1 : (r == 4) ? -ST : -(ST - 1);
                const int e2 = (r < 5) ? PLANE : -5 * PLANE;   // plane of rot r+1
                const int e3 = (r > 0) ? -PLANE : 5 * PLANE;   // plane of rot r-1
                const int base = r * PLANE + off;
                float a0x = cur[base + d],  a0y = cur[base + d + 1];
                float a1x = cur[base - d],  a1y = cur[base - d + 1];
                float a2x = cur[base + e2], a2y = cur[base + e2 + 1];
                float a3x = cur[base + e3], a3y = cur[base + e3 + 1];
                float mx = fmaxf(fmaxf(a0x, a1x), fmaxf(a2x, a3x));
                float my = fmaxf(fmaxf(a0y, a1y), fmaxf(a2y, a3y));
                rx[r] = fmaf(aa0, mx, gx[r]);
                ry[r] = fmaf(aa1, my, gy[r]);
            }
            #pragma unroll
            for (int r = 0; r < NROT; ++r) {
                const int base = r * PLANE + off;
                nxt[base]     = rx[r];
                nxt[base + 1] = ry[r];
            }
        }
        __syncthreads();
        float* tmp = cur; cur = nxt; nxt = tmp;
    }

    // ---- final gather: out[a] = m[c] * W_n[src_a(c)] at c=(rq, uu, sv)
    if (t < 4) {
        int alpha = state[b * 3 + 0];
        int su    = state[b * 3 + 1];
        int sv    = state[b * 3 + 2];
        int rq = (alpha + 1) % NROT;
        int uu = su - (sv >> 1) + 12;
        int offc = (uu + 1) * ST + sv;
        int du = ((rq == 1) | (rq == 2)) ? 1 : (((rq == 4) | (rq == 5)) ? -1 : 0);
        int dv = ((rq == 0) | (rq == 5)) ? 1 : (((rq == 2) | (rq == 3)) ? -1 : 0);
        int dd = du * ST + dv;
        int o;
        if      (t == 0) o = rq * PLANE + offc + dd;
        else if (t == 1) o = rq * PLANE + offc - dd;
        else if (t == 2) o = ((rq == 5) ? 0 : rq + 1) * PLANE + offc;
        else             o = ((rq == 0) ? 5 : rq - 1) * PLANE + offc;
        float m = 1.f - (isbf ? bf2f(o16[su * EE + sv]) : o32[su * EE + sv]);
        float res = m * cur[o];
        if (isbf) ((unsigned short*)out_)[b * 4 + t] = f2bf(res);
        else      ((float*)out_)[b * 4 + t]          = res;
    }
}

extern "C" void kernel_launch(void* const* d_in, const int* in_sizes, int n_in,
                              void* d_out, int out_size, void* d_ws, size_t ws_size,
                              hipStream_t stream) {
    const int* state = (const int*)d_in[1];
    const int* nit   = (const int*)d_in[3];
    int B = in_sizes[1] / 3;
    if (B <= 0) B = in_sizes[0] / GELEM;
    vin_kernel<<<B, NTH, 0, stream>>>(d_in[0], state, d_in[2], nit, d_out);
}

// Round 4
// 83.186 us; speedup vs baseline: 3.0513x; 1.0452x over previous
//
#include <hip/hip_runtime.h>
#include <hip/hip_bf16.h>

// Hex-grid VIN, reduced to single-field Jacobi on W = gm + 0.9*v:
//   W[c] <- gm[c] + 0.9*m[c]*max(W[fwd],W[back],W[rot+1],W[rot-1])
// Each thread owns one (u, v-pair) cell across ALL 6 rotation planes, so
// turn-neighbors (rot+-1, same cell) and the in-row halves of the v-shifts
// are register-resident from the previous sweep; only cross-row / cross-pair
// elements come from LDS. Padded plane (39x26, pad col 25, pad rows 0/38)
// keeps the hot loop bounds-check-free; pad cells have aa=g=0 so they stay 0.

#define EE    25
#define HH    37
#define ST    26
#define PR    39                  // 37 interior rows + top/bottom pad
#define PLANE (PR * ST)           // 1014
#define NROT  6
#define VOL   (NROT * PLANE)      // 6084
#define NPAIR (HH * 13)           // 481 active threads
#define NTH   512
#define GAM   0.9f
#define GELEM (NROT * EE * EE)    // 3750
#define OELEM (EE * EE)           // 625

__device__ __forceinline__ float bf2f(unsigned short h) {
    return __uint_as_float(((unsigned int)h) << 16);
}
__device__ __forceinline__ unsigned short f2bf(float f) {  // RNE
    unsigned int u = __float_as_uint(f);
    return (unsigned short)((u + 0x7FFFu + ((u >> 16) & 1u)) >> 16);
}

__global__ __launch_bounds__(NTH, 4) void vin_kernel(
    const void* __restrict__ goals_, const int* __restrict__ state,
    const void* __restrict__ obst_,  const int* __restrict__ nitp,
    void* __restrict__ out_)
{
    __shared__ float sA[VOL];
    __shared__ float sB[VOL];
    __shared__ int   sFlag;

    const int b = blockIdx.x, t = threadIdx.x;

    // ---- dtype detect (f32 {0,1} has all even-u16 positions == 0; bf16 does
    // not). All-zero-goal batches output 0 either way -> per-block safe.
    if (t == 0) sFlag = 0;
    __syncthreads();
    {
        const unsigned short* gu = (const unsigned short*)goals_;
        const unsigned short* ou = (const unsigned short*)obst_;
        unsigned int acc = 0;
        size_t gbase = (size_t)b * GELEM;              // even
        for (int e = t; e < GELEM / 2; e += NTH) acc |= gu[gbase + 2 * (size_t)e];
        size_t obase = (size_t)b * OELEM;
        size_t ostart = obase + (obase & 1);
        int ocnt = (OELEM - (int)(obase & 1) + 1) >> 1;
        for (int e = t; e < ocnt; e += NTH) acc |= ou[ostart + 2 * (size_t)e];
        if (acc) atomicOr(&sFlag, 1);
    }
    int n = nitp[0];                                    // robust scalar read
    if (n < 0 || n > 1000) {
        float f = __int_as_float(n);
        n = (f >= 0.f && f <= 1000.f) ? (int)(f + 0.5f) : 20;
    }
    __syncthreads();
    const bool isbf = (sFlag != 0);

    const unsigned short* g16 = (const unsigned short*)goals_ + (size_t)b * GELEM;
    const float*          g32 = (const float*)goals_          + (size_t)b * GELEM;
    const unsigned short* o16 = (const unsigned short*)obst_  + (size_t)b * OELEM;
    const float*          o32 = (const float*)obst_           + (size_t)b * OELEM;

    // ---- zero both buffers (pads must be 0 and stay 0)
    for (int i = t; i < VOL; i += NTH) { sA[i] = 0.f; sB[i] = 0.f; }
    __syncthreads();

    // ---- iteration-invariant constants + W_0 = gm (LDS and registers)
    const bool active = (t < NPAIR);
    const int u  = t / 13;
    const int p  = t - 13 * u;
    const int off = (u + 1) * ST + 2 * p;               // even -> 8B aligned
    float aa0 = 0.f, aa1 = 0.f;                         // gamma * m per column
    float gx[NROT], gy[NROT];                           // gm per rotation
    float wx[NROT], wy[NROT];                           // own W (prev sweep)
    #pragma unroll
    for (int r = 0; r < NROT; ++r) { gx[r] = gy[r] = wx[r] = wy[r] = 0.f; }

    if (active) {
        #pragma unroll
        for (int j = 0; j < 2; ++j) {
            int v = 2 * p + j;
            float m = 0.f;
            int i = u - 12 + (v >> 1);                  // offset row for (u,v)
            if (v < EE && i >= 0 && i < EE)
                m = 1.f - (isbf ? bf2f(o16[i * EE + v]) : o32[i * EE + v]);
            if (j == 0) aa0 = GAM * m; else aa1 = GAM * m;
            #pragma unroll
            for (int r = 0; r < NROT; ++r) {
                float g = 0.f;
                if (v < EE && i >= 0 && i < EE) {
                    float gv = isbf ? bf2f(g16[(r * EE + i) * EE + v])
                                    : g32[(r * EE + i) * EE + v];
                    g = m * gv;
                }
                if (j == 0) { gx[r] = g; wx[r] = g; }
                else        { gy[r] = g; wy[r] = g; }
                sA[r * PLANE + off + j] = g;
            }
        }
    }
    __syncthreads();

    // ---- n Jacobi sweeps: LDS only for cross-row / cross-pair neighbors
    float* cur = sA;
    float* nxt = sB;
    for (int it = 0; it < n; ++it) {
        if (active) {
            float nx[NROT], ny[NROT];
            #pragma unroll
            for (int r = 0; r < NROT; ++r) {
                const int base = r * PLANE + off;
                const int r2 = (r == 5) ? 0 : r + 1;    // turn sources
                const int r3 = (r == 0) ? 5 : r - 1;
                float a0x, a0y, a1x, a1y;
                if (r == 0) {                           // d = +1 (v-shift)
                    a0x = wy[0];        a0y = cur[base + 2];
                    a1x = cur[base - 1]; a1y = wx[0];
                } else if (r == 3) {                    // d = -1
                    a0x = cur[base - 1]; a0y = wx[3];
                    a1x = wy[3];        a1y = cur[base + 2];
                } else {                                 // cross-row shifts
                    const int d = (r == 1) ? ST : (r == 2) ? (ST - 1)
                                : (r == 4) ? -ST : -(ST - 1);
                    a0x = cur[base + d]; a0y = cur[base + d + 1];
                    a1x = cur[base - d]; a1y = cur[base - d + 1];
                }
                float mx = fmaxf(fmaxf(a0x, a1x), fmaxf(wx[r2], wx[r3]));
                float my = fmaxf(fmaxf(a0y, a1y), fmaxf(wy[r2], wy[r3]));
                nx[r] = fmaf(aa0, mx, gx[r]);
                ny[r] = fmaf(aa1, my, gy[r]);
            }
            #pragma unroll
            for (int r = 0; r < NROT; ++r) {
                const int base = r * PLANE + off;
                nxt[base]     = nx[r];
                nxt[base + 1] = ny[r];
                wx[r] = nx[r];
                wy[r] = ny[r];
            }
        }
        __syncthreads();
        float* tmp = cur; cur = nxt; nxt = tmp;
    }

    // ---- final gather: out[a] = m[c] * W_n[src_a(c)] at c=(rq, uu, sv)
    if (t < 4) {
        int alpha = state[b * 3 + 0];
        int su    = state[b * 3 + 1];
        int sv    = state[b * 3 + 2];
        int rq = (alpha + 1) % NROT;
        int uu = su - (sv >> 1) + 12;
        int offc = (uu + 1) * ST + sv;
        int du = ((rq == 1) | (rq == 2)) ? 1 : (((rq == 4) | (rq == 5)) ? -1 : 0);
        int dv = ((rq == 0) | (rq == 5)) ? 1 : (((rq == 2) | (rq == 3)) ? -1 : 0);
        int dd = du * ST + dv;
        int o;
        if      (t == 0) o = rq * PLANE + offc + dd;
        else if (t == 1) o = rq * PLANE + offc - dd;
        else if (t == 2) o = ((rq == 5) ? 0 : rq + 1) * PLANE + offc;
        else             o = ((rq == 0) ? 5 : rq - 1) * PLANE + offc;
        float m = 1.f - (isbf ? bf2f(o16[su * EE + sv]) : o32[su * EE + sv]);
        float res = m * cur[o];
        if (isbf) ((unsigned short*)out_)[b * 4 + t] = f2bf(res);
        else      ((float*)out_)[b * 4 + t]          = res;
    }
}

extern "C" void kernel_launch(void* const* d_in, const int* in_sizes, int n_in,
                              void* d_out, int out_size, void* d_ws, size_t ws_size,
                              hipStream_t stream) {
    const int* state = (const int*)d_in[1];
    const int* nit   = (const int*)d_in[3];
    int B = in_sizes[1] / 3;
    if (B <= 0) B = in_sizes[0] / GELEM;
    vin_kernel<<<B, NTH, 0, stream>>>(d_in[0], state, d_in[2], nit, d_out);
}